// Round 5
// baseline (151.604 us; speedup 1.0000x reference)
//
#include <hip/hip_runtime.h>
#include <math.h>

#define M 50
#define SQRT5 2.2360679774997896f

__constant__ float c_zscale[5] = {0.25f, 0.2f, 0.08f, 400.0f, 10.0f};
__constant__ float c_zshift[5] = {0.0f, 0.0f, 0.0f, 800.0f, 12.0f};

#if __has_builtin(__builtin_amdgcn_sqrtf)
__device__ __forceinline__ float fsqrt(float x) { return __builtin_amdgcn_sqrtf(x); }
#else
__device__ __forceinline__ float fsqrt(float x) { return sqrtf(x); }
#endif

#if __has_builtin(__builtin_amdgcn_exp2f)
__device__ __forceinline__ float fexp2(float x) { return __builtin_amdgcn_exp2f(x); }
#else
__device__ __forceinline__ float fexp2(float x) { return exp2f(x); }
#endif

typedef float f32x16 __attribute__((ext_vector_type(16)));

// ---------------------------------------------------------------------------
// ws layout (floats):
//   [0    .. 1275)  Ap: packed upper-tri of pv^2*(A + A^T), diag = pv^2*A_mm
//   [1280 .. 1530)  Zb[m][j] = -2*sqrt5*Zs[m][j]
//   [1536 .. 1586)  z2s[m]   = |sqrt5*Zs[m]|^2 + 5e-8   (epsilon folded)
//   [1600 .. 1605)  ils[j]   = sqrt5 * inv_ls[j]
//   [1606]          prior_var
// ---------------------------------------------------------------------------
// Setup: 256 threads; thread t owns 20 consecutive elements of the 50x100
// augmented matrix, all in ONE row (irow = t*20/100), cols j0..j0+19.
// Pipelined Gauss-Jordan: each phase updates w.r.t. pivot p using the
// row/col published the previous phase, and publishes pivot p+1's row/col
// from the freshly updated values -> ONE barrier per pivot (50 total).
// ---------------------------------------------------------------------------
__global__ __launch_bounds__(256) void gp_setup(const float* __restrict__ log_ls,
                                                const float* __restrict__ log_var,
                                                const float* __restrict__ zraw,
                                                float* __restrict__ ws) {
    __shared__ float s_ils[5];
    __shared__ float s_pv;
    __shared__ float s_Zs[M * 5];
    __shared__ float s_f[2][M];        // col p (raw, post prev update)
    __shared__ float s_row[2][2 * M];  // row p (raw, post prev update)
    __shared__ float s_A[M][M];        // final inverse

    const int t = threadIdx.x;

    if (t == 0) s_pv = expf(log_var[0]);
    if (t < 5)  s_ils[t] = 1.0f / (expf(log_ls[t]) + 1e-8f);
    __syncthreads();
    if (t < M * 5) {
        int j = t % 5;
        s_Zs[t] = (tanhf(zraw[t]) * c_zscale[j] + c_zshift[j]) * s_ils[j];
    }
    __syncthreads();
    const float pv = s_pv;

    const int  ebase = t * 20;
    const bool act   = (ebase < M * 2 * M);   // t < 250
    const int  irow  = act ? (ebase / 100) : 0;
    const int  j0    = ebase % 100;           // in {0,20,40,60,80}

    // Build owned row segment of augmented [K+1e-4 I | I]
    float r[20];
    #pragma unroll
    for (int kk = 0; kk < 20; ++kk) {
        int j = j0 + kk;
        float v = 0.0f;
        if (act) {
            if (j < M) {
                float d2 = 0.0f;
                #pragma unroll
                for (int q = 0; q < 5; ++q) {
                    float df = s_Zs[irow * 5 + q] - s_Zs[j * 5 + q];
                    d2 = fmaf(df, df, d2);
                }
                float d = fsqrt(d2 + 1e-8f);
                float s = SQRT5 * d;
                v = pv * (1.0f + s + (5.0f / 3.0f) * (d * d)) * expf(-s)
                    + ((irow == j) ? 1e-4f : 0.0f);
            } else {
                v = ((j - M) == irow) ? 1.0f : 0.0f;
            }
        }
        r[kk] = v;
    }

    // Publish pivot 0's column and row
    if (act) {
        if (j0 == 0) s_f[0][irow] = r[0];
        if (irow == 0) {
            #pragma unroll
            for (int kk = 0; kk < 20; ++kk) s_row[0][j0 + kk] = r[kk];
        }
    }
    __syncthreads();

    int buf = 0;
    for (int p = 0; p < M; ++p) {
        const float rp     = 1.0f / s_row[buf][p];
        const float colf   = act ? s_f[buf][irow] : 0.0f;   // raw a[irow][p]
        const bool  isprow = (irow == p) && act;
        float* __restrict__ sfn = s_f[buf ^ 1];
        float* __restrict__ srn = s_row[buf ^ 1];
        const bool pub = (p + 1 < M);
        #pragma unroll
        for (int kk = 0; kk < 20; ++kk) {
            int j = j0 + kk;
            float rowv = rp * s_row[buf][j];               // normalized a[p][j]
            float v = isprow ? rowv : fmaf(-colf, rowv, r[kk]);
            r[kk] = v;
            if (act && pub) {
                if (j == p + 1)     sfn[irow] = v;         // next pivot column
                if (irow == p + 1)  srn[j]    = v;         // next pivot row
            }
        }
        __syncthreads();
        buf ^= 1;
    }

    // Gather right half (the inverse) into LDS
    if (act) {
        #pragma unroll
        for (int kk = 0; kk < 20; ++kk) {
            int j = j0 + kk;
            if (j >= M) s_A[irow][j - M] = r[kk];
        }
    }
    __syncthreads();

    // Pack upper-tri of pv^2*(A + A^T), diag = pv^2*A_mm
    const float pv2 = pv * pv;
    for (int e = t; e < M * M; e += 256) {
        int m = e / M, n = e % M;
        if (n >= m) {
            int off = m * M - (m * (m - 1)) / 2 + (n - m);
            float v = (m == n) ? s_A[m][m] : (s_A[m][n] + s_A[n][m]);
            ws[off] = pv2 * v;
        }
    }
    if (t < M * 5) ws[1280 + t] = -2.0f * SQRT5 * s_Zs[t];
    if (t < M) {
        float z2 = 0.0f;
        #pragma unroll
        for (int q = 0; q < 5; ++q) {
            float v = SQRT5 * s_Zs[t * 5 + q];
            z2 = fmaf(v, v, z2);
        }
        ws[1536 + t] = z2 + 5e-8f;
    }
    if (t < 5)  ws[1600 + t] = SQRT5 * s_ils[t];
    if (t == 0) ws[1606] = pv;
}

// ---------------------------------------------------------------------------
// Main kernel: one thread per query point. k[50] held as 3x f32x16 + 2
// scalars (all compile-time indices after unroll). One multi-operand asm
// pin between k-gen and quad form + shrinking re-pins force arch-VGPR
// residency (round 3/4 pathology: allocator parked k in AGPRs behind
// VGPR_Count=32/52, paying ~1275 v_accvgpr_read in the quad form).
// ---------------------------------------------------------------------------
#define KGET(n) ((n) < 16 ? ka[(n)] : (n) < 32 ? kb[(n) - 16] : \
                 (n) < 48 ? kc[(n) - 32] : ((n) == 48 ? kd0 : kd1))

__global__ __launch_bounds__(256)
__attribute__((amdgpu_waves_per_eu(1, 4)))
void gp_var(const float* __restrict__ x,
            const float* __restrict__ ws,
            float* __restrict__ out, int B) {
    __shared__ float sx[1280];
    const int t = threadIdx.x;
    const int gid = blockIdx.x * 256 + t;
    const long long base = (long long)blockIdx.x * 1280;

    // Coalesced float4 staging of this block's 256x5 inputs
    {
        const long long tot = (long long)B * 5;
        const float4* xv = (const float4*)(x + base);
        for (int i = t; i < 320; i += 256) {
            if (base + (long long)i * 4 + 3 < tot) {
                ((float4*)sx)[i] = xv[i];
            }
        }
    }
    __syncthreads();
    if (gid >= B) return;

    const float* __restrict__ Ap  = ws;
    const float* __restrict__ Zb  = ws + 1280;
    const float* __restrict__ z2s = ws + 1536;
    const float* __restrict__ ils = ws + 1600;
    const float pv = ws[1606];

    float xs[5];
    #pragma unroll
    for (int j = 0; j < 5; ++j) xs[j] = sx[t * 5 + j] * ils[j];

    float x2 = 0.0f;
    #pragma unroll
    for (int j = 0; j < 5; ++j) x2 = fmaf(xs[j], xs[j], x2);

    f32x16 ka, kb, kc;
    float kd0, kd1;
    #pragma unroll
    for (int m = 0; m < M; ++m) {
        float u = x2 + z2s[m];
        #pragma unroll
        for (int j = 0; j < 5; ++j) u = fmaf(Zb[m * 5 + j], xs[j], u);
        u = fmaxf(u, 5e-8f);
        float s = fsqrt(u);
        float e = fexp2(s * -1.4426950408889634f);          // exp(-s)
        float kv = fmaf(u, (1.0f / 3.0f), 1.0f + s) * e;
        if      (m < 16)  ka[m]      = kv;
        else if (m < 32)  kb[m - 16] = kv;
        else if (m < 48)  kc[m - 32] = kv;
        else if (m == 48) kd0 = kv;
        else              kd1 = kv;
    }

    // Pin all 50 k values into arch VGPRs simultaneously
    asm volatile("" : "+v"(ka), "+v"(kb), "+v"(kc), "+v"(kd0), "+v"(kd1));

    // red = k'^T Ap k' via packed upper-tri; dual accumulators halve the
    // per-row FMA dependency chain.
    float red = 0.0f;
    int idx = 0;
    #pragma unroll
    for (int m = 0; m < M; ++m) {
        if (m == 16) asm volatile("" : "+v"(kb), "+v"(kc), "+v"(kd0), "+v"(kd1));
        if (m == 32) asm volatile("" : "+v"(kc), "+v"(kd0), "+v"(kd1));
        float t0 = 0.0f, t1 = 0.0f;
        #pragma unroll
        for (int n = m; n < M; ++n) {
            float kn = KGET(n);
            if (((n - m) & 1) == 0) t0 = fmaf(Ap[idx], kn, t0);
            else                    t1 = fmaf(Ap[idx], kn, t1);
            ++idx;
        }
        red = fmaf(KGET(m), t0 + t1, red);
    }

    out[gid] = fsqrt(fmaxf(pv - red, 1e-6f));
}

extern "C" void kernel_launch(void* const* d_in, const int* in_sizes, int n_in,
                              void* d_out, int out_size, void* d_ws, size_t ws_size,
                              hipStream_t stream) {
    const float* x    = (const float*)d_in[0];
    const float* ll   = (const float*)d_in[1];
    const float* lv   = (const float*)d_in[2];
    const float* zraw = (const float*)d_in[3];
    float* out = (float*)d_out;
    float* ws  = (float*)d_ws;

    const int B = in_sizes[0] / 5;

    hipLaunchKernelGGL(gp_setup, dim3(1), dim3(256), 0, stream, ll, lv, zraw, ws);
    const int grid = (B + 255) / 256;
    hipLaunchKernelGGL(gp_var, dim3(grid), dim3(256), 0, stream, x, ws, out, B);
}